// Round 6
// baseline (146.911 us; speedup 1.0000x reference)
//
#include <hip/hip_runtime.h>
#include <hip/hip_bf16.h>

typedef __attribute__((ext_vector_type(8))) short short8;
typedef __attribute__((ext_vector_type(4))) float f32x4;

#define DIM_D 256
#define DIM_O 256
#define DIM_K 8
#define BM 128
#define NSTEP 64   // 64 ks-steps of K=32 (4 d-values each) cover D*K = 2048

__device__ __forceinline__ unsigned short f2bf(float f) {
    union { float f; unsigned int u; } v; v.f = f;
    unsigned int u = v.u;
    u += 0x7fffu + ((u >> 16) & 1u);   // round-to-nearest-even
    return (unsigned short)(u >> 16);
}

// v_cvt_pk_bf16_f32: dst.lo = bf16(lo), dst.hi = bf16(hi), RNE — 1 instr
__device__ __forceinline__ unsigned int cvt_pk_bf16(float lo, float hi) {
    unsigned int r;
    asm("v_cvt_pk_bf16_f32 %0, %1, %2" : "=v"(r) : "v"(lo), "v"(hi));
    return r;
}

// Pack cheby_coeffs (O, D, K) f32 -> W_packed bf16 in MFMA B-fragment order:
// wp[ksg][F][lane][j] = c[o = 16F + (lane&15)][d = ksg*4 + (lane>>4)][k = j]
__global__ void pack_w_kernel(const float* __restrict__ coeffs,
                              unsigned short* __restrict__ wp) {
    int e = blockIdx.x * 256 + threadIdx.x;      // 0 .. 524287
    int j   = e & 7;
    int l   = (e >> 3) & 63;
    int F   = (e >> 9) & 15;
    int ksg = e >> 13;                           // 0..63
    int o = F * 16 + (l & 15);
    int d = ksg * 4 + (l >> 4);
    wp[e] = f2bf(coeffs[(size_t)(o * DIM_D + d) * DIM_K + j]);
}

// tanh + Chebyshev recurrence + packed-bf16 A-fragment for one x value
__device__ __forceinline__ short8 cheb_frag(float xs) {
    // tanh(x) = 1 - 2/(e^{2x}+1); |x| <= ~6 for randn inputs, no clamp
    float e2 = __expf(2.f * xs);
    float r  = __builtin_amdgcn_rcpf(e2 + 1.f);
    float T1 = __builtin_fmaf(-2.f, r, 1.f);
    float tx = T1 + T1;
    float T2 = __builtin_fmaf(tx, T1, -1.f);
    float T3 = __builtin_fmaf(tx, T2, -T1);
    float T4 = __builtin_fmaf(tx, T3, -T2);
    float T5 = __builtin_fmaf(tx, T4, -T3);
    float T6 = __builtin_fmaf(tx, T5, -T4);
    float T7 = __builtin_fmaf(tx, T6, -T5);
    union { unsigned int u[4]; short8 s; } tv;
    tv.u[0] = cvt_pk_bf16(1.f, T1);
    tv.u[1] = cvt_pk_bf16(T2, T3);
    tv.u[2] = cvt_pk_bf16(T4, T5);
    tv.u[3] = cvt_pk_bf16(T6, T7);
    return tv.s;
}

// LDS-free, barrier-free: each lane computes its own MFMA A-fragments.
// Lane l covers (row = rt*16 + (l&15), d = step*4 + (l>>4)), all 8 orders.
__global__ __launch_bounds__(256, 2) void cfkan_kernel(
    const float* __restrict__ x,
    const unsigned short* __restrict__ wp,
    const float* __restrict__ bias,
    float* __restrict__ y)
{
    const int t = threadIdx.x;
    const int w = t >> 6;            // wave 0..3 -> output cols [64w, 64w+64)
    const int l = t & 63;
    const int rlane = l & 15;
    const int g = l >> 4;            // 0..3 : d-offset within a ks-step
    const int row0 = blockIdx.x * BM;

    const short8* wp8 = (const short8*)wp;
    const short8* wpb = wp8 + (w * 4) * 64 + l;          // + step*1024 + f*64
    const float*  xb  = x + (size_t)(row0 + rlane) * DIM_D + g; // + rt*4096 + step*4

    f32x4 acc[8][4];
    #pragma unroll
    for (int rt = 0; rt < 8; ++rt)
        #pragma unroll
        for (int f = 0; f < 4; ++f)
            acc[rt][f] = (f32x4){0.f, 0.f, 0.f, 0.f};

    float  xv[8], xn[8];
    short8 bc[4], bn[4];

    // ---- prologue: loads for step 0 ----
    #pragma unroll
    for (int rt = 0; rt < 8; ++rt) xv[rt] = xb[rt * 16 * DIM_D];
    #pragma unroll
    for (int f = 0; f < 4; ++f) bc[f] = wpb[f * 64];

    // ---- main loop: free-running, no barriers ----
    #pragma unroll 1
    for (int s = 0; s < NSTEP; ++s) {
        // issue next step's loads (clamped at the end; extra reload harmless)
        const int sn = (s + 1 < NSTEP) ? s + 1 : NSTEP - 1;
        #pragma unroll
        for (int rt = 0; rt < 8; ++rt)
            xn[rt] = xb[rt * 16 * DIM_D + sn * 4];
        #pragma unroll
        for (int f = 0; f < 4; ++f)
            bn[f] = wpb[sn * 1024 + f * 64];

        // compute all 8 A-fragments for this step (VALU, hides under MFMA
        // of the other wave on this SIMD — no barrier forces co-phasing)
        short8 frag[8];
        #pragma unroll
        for (int rt = 0; rt < 8; ++rt)
            frag[rt] = cheb_frag(xv[rt]);

        __builtin_amdgcn_s_setprio(1);
        #pragma unroll
        for (int rt = 0; rt < 8; ++rt)
            #pragma unroll
            for (int f = 0; f < 4; ++f)
                acc[rt][f] = __builtin_amdgcn_mfma_f32_16x16x32_bf16(
                    frag[rt], bc[f], acc[rt][f], 0, 0, 0);
        __builtin_amdgcn_s_setprio(0);

        #pragma unroll
        for (int rt = 0; rt < 8; ++rt) xv[rt] = xn[rt];
        #pragma unroll
        for (int f = 0; f < 4; ++f) bc[f] = bn[f];
    }

    // ---- epilogue: add bias, store f32 ----
    #pragma unroll
    for (int f = 0; f < 4; ++f) {
        const int col = w * 64 + f * 16 + (l & 15);
        const float bv = bias[col];
        #pragma unroll
        for (int rt = 0; rt < 8; ++rt) {
            const int grow = row0 + rt * 16 + (l >> 4) * 4;
            #pragma unroll
            for (int q = 0; q < 4; ++q)
                y[(size_t)(grow + q) * DIM_O + col] = acc[rt][f][q] + bv;
        }
    }
}

extern "C" void kernel_launch(void* const* d_in, const int* in_sizes, int n_in,
                              void* d_out, int out_size, void* d_ws, size_t ws_size,
                              hipStream_t stream) {
    const float* x      = (const float*)d_in[0];
    const float* coeffs = (const float*)d_in[1];
    const float* bias   = (const float*)d_in[2];
    float* y = (float*)d_out;
    unsigned short* wp = (unsigned short*)d_ws;   // 2048*256 bf16 = 1 MB

    const int n_tokens = in_sizes[0] / DIM_D;     // 65536

    pack_w_kernel<<<(DIM_O * DIM_D * DIM_K) / 256, 256, 0, stream>>>(coeffs, wp);
    cfkan_kernel<<<n_tokens / BM, 256, 0, stream>>>(x, wp, bias, y);
}

// Round 7
// 71.192 us; speedup vs baseline: 2.0636x; 2.0636x over previous
//
#include <hip/hip_runtime.h>
#include <hip/hip_bf16.h>

typedef __attribute__((ext_vector_type(8))) short short8;
typedef __attribute__((ext_vector_type(4))) float f32x4;

#define DIM_D 256
#define DIM_O 256
#define DIM_K 8
#define BM 128
#define DCHUNK 16
#define NCHUNK (DIM_D / DCHUNK)   // 16

__device__ __forceinline__ unsigned short f2bf(float f) {
    union { float f; unsigned int u; } v; v.f = f;
    unsigned int u = v.u;
    u += 0x7fffu + ((u >> 16) & 1u);   // round-to-nearest-even
    return (unsigned short)(u >> 16);
}

// v_cvt_pk_bf16_f32: dst.lo = bf16(lo), dst.hi = bf16(hi), RNE — 1 instr
__device__ __forceinline__ unsigned int cvt_pk_bf16(float lo, float hi) {
    unsigned int r;
    asm("v_cvt_pk_bf16_f32 %0, %1, %2" : "=v"(r) : "v"(lo), "v"(hi));
    return r;
}

// Pack cheby_coeffs (O, D, K) f32 -> W_packed bf16 in MFMA B-fragment order:
// wp[ksg][F][lane][j] = c[o = 16F + (lane&15)][d = ksg*4 + (lane>>4)][k = j]
__global__ void pack_w_kernel(const float* __restrict__ coeffs,
                              unsigned short* __restrict__ wp) {
    int e = blockIdx.x * 256 + threadIdx.x;      // 0 .. 524287
    int j   = e & 7;
    int l   = (e >> 3) & 63;
    int F   = (e >> 9) & 15;
    int ksg = e >> 13;                           // 0..63
    int o = F * 16 + (l & 15);
    int d = ksg * 4 + (l >> 4);
    wp[e] = f2bf(coeffs[(size_t)(o * DIM_D + d) * DIM_K + j]);
}

// tanh + Chebyshev recurrence + packed-bf16 + LDS write for ONE (row,d)
__device__ __forceinline__ void cheb_store(float xs, unsigned short* dst) {
    // tanh(x) = 1 - 2/(e^{2x}+1); |x| <= ~6 for randn inputs, no clamp
    float e2 = __expf(2.f * xs);
    float r  = __builtin_amdgcn_rcpf(e2 + 1.f);
    float T1 = __builtin_fmaf(-2.f, r, 1.f);
    float tx = T1 + T1;
    float T2 = __builtin_fmaf(tx, T1, -1.f);
    float T3 = __builtin_fmaf(tx, T2, -T1);
    float T4 = __builtin_fmaf(tx, T3, -T2);
    float T5 = __builtin_fmaf(tx, T4, -T3);
    float T6 = __builtin_fmaf(tx, T5, -T4);
    float T7 = __builtin_fmaf(tx, T6, -T5);
    union { unsigned int u[4]; short8 s; } tv;
    tv.u[0] = cvt_pk_bf16(1.f, T1);
    tv.u[1] = cvt_pk_bf16(T2, T3);
    tv.u[2] = cvt_pk_bf16(T4, T5);
    tv.u[3] = cvt_pk_bf16(T6, T7);
    *(short8*)dst = tv.s;
}

__global__ __launch_bounds__(256, 2) void cfkan_kernel(
    const float* __restrict__ x,
    const unsigned short* __restrict__ wp,
    const float* __restrict__ bias,
    float* __restrict__ y)
{
    // double-buffered A tile, XOR-swizzled slots (slot = d ^ (row&15)); 64 KB
    __shared__ unsigned short Abuf[2][BM][128];

    const int t = threadIdx.x;
    const int w = t >> 6;            // wave 0..3 -> output cols [64w, 64w+64)
    const int l = t & 63;
    const int rl = l & 15;
    const int g  = l >> 4;           // 0..3 : d-offset within a ks-step
    const int row0 = blockIdx.x * BM;
    const short8* wp8 = (const short8*)wp;

    const int lrow  = t >> 1;        // 0..127 (row this thread stages)
    const int dpart = (t & 1) * 8;   // which 8 of the 16 chunk-d's
    const float* xrow = x + (size_t)(row0 + lrow) * DIM_D + dpart;

    f32x4 acc[8][4];
    #pragma unroll
    for (int rt = 0; rt < 8; ++rt)
        #pragma unroll
        for (int f = 0; f < 4; ++f)
            acc[rt][f] = (f32x4){0.f, 0.f, 0.f, 0.f};

    // ---- prologue: B(ks0,ks1) prefetch, stage chunk0, preload x(chunk1) ----
    short8 bC[4], bN[4];
    #pragma unroll
    for (int f = 0; f < 4; ++f) {
        bC[f] = wp8[(0 * 16 + w * 4 + f) * 64 + l];   // ks0
        bN[f] = wp8[(1 * 16 + w * 4 + f) * 64 + l];   // ks1
    }
    float xv[8];
    {
        float4 a0 = *(const float4*)(xrow);
        float4 a1 = *(const float4*)(xrow + 4);
        float xs[8] = {a0.x, a0.y, a0.z, a0.w, a1.x, a1.y, a1.z, a1.w};
        #pragma unroll
        for (int p = 0; p < 8; ++p)
            cheb_store(xs[p], &Abuf[0][lrow][(((dpart + p) ^ (lrow & 15))) * 8]);
        float4 b0 = *(const float4*)(xrow + DCHUNK);
        float4 b1 = *(const float4*)(xrow + DCHUNK + 4);
        xv[0] = b0.x; xv[1] = b0.y; xv[2] = b0.z; xv[3] = b0.w;
        xv[4] = b1.x; xv[5] = b1.y; xv[6] = b1.z; xv[7] = b1.w;
    }
    __syncthreads();

// 4 ds_read_b128: A-fragments for (KS, half H) -> rows (H*4+rt)*16+rl
#define READ4(DST, ABUF, KS, H) do {                                       \
    const int _so = (((KS) * 4 + g) ^ rl) * 8;                             \
    DST[0] = *(const short8*)&ABUF[((H) * 4 + 0) * 16 + rl][_so];          \
    DST[1] = *(const short8*)&ABUF[((H) * 4 + 1) * 16 + rl][_so];          \
    DST[2] = *(const short8*)&ABUF[((H) * 4 + 2) * 16 + rl][_so];          \
    DST[3] = *(const short8*)&ABUF[((H) * 4 + 3) * 16 + rl][_so];          \
} while (0)

#define MFMA16(RS, BB, BASE) do {                                          \
    __builtin_amdgcn_s_setprio(1);                                         \
    _Pragma("unroll")                                                      \
    for (int _rt = 0; _rt < 4; ++_rt)                                      \
        _Pragma("unroll")                                                  \
        for (int _f = 0; _f < 4; ++_f)                                     \
            acc[(BASE) + _rt][_f] = __builtin_amdgcn_mfma_f32_16x16x32_bf16(\
                RS[_rt], BB[_f], acc[(BASE) + _rt][_f], 0, 0, 0);          \
    __builtin_amdgcn_s_setprio(0);                                         \
} while (0)

#define LOADB(DST, KSG) do {                                               \
    DST[0] = wp8[((KSG) * 16 + w * 4 + 0) * 64 + l];                       \
    DST[1] = wp8[((KSG) * 16 + w * 4 + 1) * 64 + l];                       \
    DST[2] = wp8[((KSG) * 16 + w * 4 + 2) * 64 + l];                       \
    DST[3] = wp8[((KSG) * 16 + w * 4 + 3) * 64 + l];                       \
} while (0)

#define CHEB(P, ANX) \
    cheb_store(xv[P], &ANX[lrow][(((dpart + (P)) ^ (lrow & 15))) * 8])

    short8 rE[4], rO[4];
    READ4(rE, Abuf[0], 0, 0);
    READ4(rO, Abuf[0], 0, 1);

    // ---- main loop: 8 fine-grained phases per chunk, 1 barrier per chunk ----
    #pragma unroll 1
    for (int c = 0; c < NCHUNK; ++c) {
        const int buf = c & 1;
        const unsigned short (*A)[128] = Abuf[buf];
        unsigned short (*ANX)[128] = Abuf[buf ^ 1];
        const int c4  = c * 4;
        const int nc4 = ((c + 1) & (NCHUNK - 1)) * 4;  // wraps at end; harmless
        const int sn  = (c + 2 < NCHUNK) ? c + 2 : NCHUNK - 1;
        float4 xn0, xn1;

        // P0
        MFMA16(rE, bC, 0);
        READ4(rE, A, 1, 0);
        xn0 = *(const float4*)(xrow + sn * DCHUNK);
        CHEB(0, ANX);
        // P1
        MFMA16(rO, bC, 4);
        READ4(rO, A, 1, 1);
        xn1 = *(const float4*)(xrow + sn * DCHUNK + 4);
        LOADB(bC, c4 + 2);
        CHEB(1, ANX);
        // P2
        MFMA16(rE, bN, 0);
        READ4(rE, A, 2, 0);
        CHEB(2, ANX);
        // P3
        MFMA16(rO, bN, 4);
        READ4(rO, A, 2, 1);
        LOADB(bN, c4 + 3);
        CHEB(3, ANX);
        // P4
        MFMA16(rE, bC, 0);
        READ4(rE, A, 3, 0);
        CHEB(4, ANX);
        // P5
        MFMA16(rO, bC, 4);
        READ4(rO, A, 3, 1);
        LOADB(bC, nc4 + 0);
        CHEB(5, ANX);
        // P6
        MFMA16(rE, bN, 0);
        CHEB(6, ANX);
        // P7
        MFMA16(rO, bN, 4);
        LOADB(bN, nc4 + 1);
        CHEB(7, ANX);

        xv[0] = xn0.x; xv[1] = xn0.y; xv[2] = xn0.z; xv[3] = xn0.w;
        xv[4] = xn1.x; xv[5] = xn1.y; xv[6] = xn1.z; xv[7] = xn1.w;

        __syncthreads();
        // prefetch next chunk's ks0 fragments (reads cross into next iter)
        READ4(rE, ANX, 0, 0);
        READ4(rO, ANX, 0, 1);
    }

    // ---- epilogue: add bias, store f32 ----
    #pragma unroll
    for (int f = 0; f < 4; ++f) {
        const int col = w * 64 + f * 16 + (l & 15);
        const float bv = bias[col];
        #pragma unroll
        for (int rt = 0; rt < 8; ++rt) {
            const int grow = row0 + rt * 16 + (l >> 4) * 4;
            #pragma unroll
            for (int q = 0; q < 4; ++q)
                y[(size_t)(grow + q) * DIM_O + col] = acc[rt][f][q] + bv;
        }
    }
#undef READ4
#undef MFMA16
#undef LOADB
#undef CHEB
}

extern "C" void kernel_launch(void* const* d_in, const int* in_sizes, int n_in,
                              void* d_out, int out_size, void* d_ws, size_t ws_size,
                              hipStream_t stream) {
    const float* x      = (const float*)d_in[0];
    const float* coeffs = (const float*)d_in[1];
    const float* bias   = (const float*)d_in[2];
    float* y = (float*)d_out;
    unsigned short* wp = (unsigned short*)d_ws;   // 2048*256 bf16 = 1 MB

    const int n_tokens = in_sizes[0] / DIM_D;     // 65536

    pack_w_kernel<<<(DIM_O * DIM_D * DIM_K) / 256, 256, 0, stream>>>(coeffs, wp);
    cfkan_kernel<<<n_tokens / BM, 256, 0, stream>>>(x, wp, bias, y);
}